// Round 2
// baseline (994.877 us; speedup 1.0000x reference)
//
#include <hip/hip_runtime.h>

// out = 0.5*ve[batch] + 0.5 * softmax((lang[batch]@W) @ keyᵀ) @ ve
// (bias b cancels in softmax: scores = qW@keyᵀ + (q·b)1ᵀ, constant per row)
// All GEMMs bf16 MFMA 16x16x32, f32 accumulate. Vocab processed in chunks to
// bound workspace; chunk size chosen at runtime from ws_size (deterministic).

#define DIM   1024
#define VOCAB 32000
#define NTOK  4096
#define KSPLIT 2

typedef unsigned short u16;
typedef __attribute__((ext_vector_type(8))) __bf16 bf16x8;
typedef __attribute__((ext_vector_type(4))) float  f32x4;
typedef __attribute__((ext_vector_type(8))) u16    u16x8;
typedef __attribute__((ext_vector_type(4))) u16    u16x4;

__device__ __forceinline__ u16 f2bf(float f) {  // round-to-nearest-even
  unsigned u = __float_as_uint(f);
  u += 0x7FFFu + ((u >> 16) & 1u);
  return (u16)(u >> 16);
}
__device__ __forceinline__ float bf2f(u16 s) {
  return __uint_as_float(((unsigned)s) << 16);
}

// ---------------- conversion / gather ----------------

__global__ void cvt_f32_bf16(const float* __restrict__ in, u16* __restrict__ out) {
  size_t i = (size_t)blockIdx.x * 256 + threadIdx.x;
  float4 v = ((const float4*)in)[i];
  u16x4 o; o[0]=f2bf(v.x); o[1]=f2bf(v.y); o[2]=f2bf(v.z); o[3]=f2bf(v.w);
  ((u16x4*)out)[i] = o;
}

__global__ void gather_q(const int* __restrict__ batch, const float* __restrict__ lang,
                         u16* __restrict__ q) {
  int row = blockIdx.x;
  int src = batch[row];
  int t = threadIdx.x;                      // 256 threads * 4 floats = 1024
  float4 v = *(const float4*)(lang + (size_t)src * DIM + (t << 2));
  u16x4 o; o[0]=f2bf(v.x); o[1]=f2bf(v.y); o[2]=f2bf(v.z); o[3]=f2bf(v.w);
  *(u16x4*)(q + (size_t)row * DIM + (t << 2)) = o;
}

// out[c][r] = bf16(in[r][c]) ; 64x64 tiles via LDS. grid = (R/64, C/64)
__global__ void transpose_cvt(const float* __restrict__ in, u16* __restrict__ out,
                              int ldin, int ldout) {
  __shared__ u16 t[64][72];
  int r0 = blockIdx.x << 6;                 // input row base
  int c0 = blockIdx.y << 6;                 // input col base
  int tid = threadIdx.x;
  #pragma unroll
  for (int p = 0; p < 4; ++p) {
    int r = (p << 4) + (tid >> 4);          // 0..63
    int c = (tid & 15) << 2;                // 0..60
    float4 v = *(const float4*)(in + (size_t)(r0 + r) * ldin + c0 + c);
    t[c+0][r] = f2bf(v.x);
    t[c+1][r] = f2bf(v.y);
    t[c+2][r] = f2bf(v.z);
    t[c+3][r] = f2bf(v.w);
  }
  __syncthreads();
  #pragma unroll
  for (int qq = 0; qq < 2; ++qq) {
    int rr = tid >> 2;                      // 0..63 (out row, input-col-local)
    int cc = (((tid & 3) << 1) + qq) << 3;  // 0..56 (out col, input-row-local)
    u16x8 w;
    #pragma unroll
    for (int j = 0; j < 8; ++j) w[j] = t[rr][cc + j];
    *(u16x8*)(out + (size_t)(c0 + rr) * ldout + r0 + cc) = w;
  }
}

// ---------------- GEMM: C[M,N] = A[M,K] @ B[N,K]^T ----------------
// MODE 1: C = bf16(exp(acc))      (P chunk)
// MODE 2: C(f32) += acc           (numer partials, split-K via blockIdx.z)
// MODE 3: C = bf16(acc)           (qW)

template<int MODE>
__global__ void gemm_bt(const u16* __restrict__ A, const u16* __restrict__ B,
                        void* __restrict__ Cout, int K, int kSteps, int ldc) {
  __shared__ u16 As[128 * 32];
  __shared__ u16 Bs[128 * 32];
  const int tid  = threadIdx.x;
  const int lane = tid & 63;
  const int wid  = tid >> 6;
  const int wr   = wid >> 1, wc = wid & 1;
  const int row0 = blockIdx.x << 7;
  const int col0 = blockIdx.y << 7;
  const int kbase = blockIdx.z * (kSteps << 5);

  f32x4 zero = {0.f, 0.f, 0.f, 0.f};
  f32x4 acc[4][4];
  #pragma unroll
  for (int m = 0; m < 4; ++m)
    #pragma unroll
    for (int n = 0; n < 4; ++n) acc[m][n] = zero;

  const int sr = lane >> 2;         // subrow 0..15 in a 16-row chunk
  const int sc = (lane & 3) << 3;   // 0,8,16,24 u16 (16B steps)

  for (int ks = 0; ks < kSteps; ++ks) {
    const int kk = kbase + (ks << 5);
    #pragma unroll
    for (int t = 0; t < 2; ++t) {
      const int i = wid * 2 + t;    // 16-row chunk 0..7
      const u16* gA = A + (size_t)(row0 + (i << 4) + sr) * K + kk + sc;
      const u16* gB = B + (size_t)(col0 + (i << 4) + sr) * K + kk + sc;
      __builtin_amdgcn_global_load_lds((const __attribute__((address_space(1))) void*)gA,
                                       (__attribute__((address_space(3))) void*)(As + i * 512),
                                       16, 0, 0);
      __builtin_amdgcn_global_load_lds((const __attribute__((address_space(1))) void*)gB,
                                       (__attribute__((address_space(3))) void*)(Bs + i * 512),
                                       16, 0, 0);
    }
    __syncthreads();

    bf16x8 a[4], b[4];
    #pragma unroll
    for (int m = 0; m < 4; ++m)
      a[m] = *(const bf16x8*)(As + ((wr << 6) + (m << 4) + (lane & 15)) * 32 + ((lane >> 4) << 3));
    #pragma unroll
    for (int n = 0; n < 4; ++n)
      b[n] = *(const bf16x8*)(Bs + ((wc << 6) + (n << 4) + (lane & 15)) * 32 + ((lane >> 4) << 3));
    #pragma unroll
    for (int m = 0; m < 4; ++m)
      #pragma unroll
      for (int n = 0; n < 4; ++n)
        acc[m][n] = __builtin_amdgcn_mfma_f32_16x16x32_bf16(a[m], b[n], acc[m][n], 0, 0, 0);
    __syncthreads();
  }

  const int r0 = row0 + (wr << 6);
  const int c0 = col0 + (wc << 6);
  const int fq = (lane >> 4) << 2;
  const int fr = lane & 15;

  if (MODE == 1) {
    u16* C = (u16*)Cout;
    #pragma unroll
    for (int m = 0; m < 4; ++m)
      #pragma unroll
      for (int n = 0; n < 4; ++n) {
        int col = c0 + (n << 4) + fr;
        #pragma unroll
        for (int j = 0; j < 4; ++j) {
          int row = r0 + (m << 4) + fq + j;
          C[(size_t)row * ldc + col] = f2bf(__expf(acc[m][n][j]));
        }
      }
  } else if (MODE == 2) {
    float* C = (float*)Cout + (size_t)blockIdx.z * NTOK * DIM;
    #pragma unroll
    for (int m = 0; m < 4; ++m)
      #pragma unroll
      for (int n = 0; n < 4; ++n) {
        int col = c0 + (n << 4) + fr;
        #pragma unroll
        for (int j = 0; j < 4; ++j) {
          int row = r0 + (m << 4) + fq + j;
          C[(size_t)row * ldc + col] += acc[m][n][j];
        }
      }
  } else {
    u16* C = (u16*)Cout;
    #pragma unroll
    for (int m = 0; m < 4; ++m)
      #pragma unroll
      for (int n = 0; n < 4; ++n) {
        int col = c0 + (n << 4) + fr;
        #pragma unroll
        for (int j = 0; j < 4; ++j) {
          int row = r0 + (m << 4) + fq + j;
          C[(size_t)row * ldc + col] = f2bf(acc[m][n][j]);
        }
      }
  }
}

// ---------------- denom accumulate: denom[row] += rowsum(P_c[row]) ----------------
__global__ void rowsum_acc(const u16* __restrict__ P, float* __restrict__ denom, int C) {
  __shared__ float red[256];
  int row = blockIdx.x;
  const u16x8* p = (const u16x8*)(P + (size_t)row * C);
  float s = 0.f;
  for (int c = threadIdx.x; c < (C >> 3); c += 256) {
    u16x8 v = p[c];
    #pragma unroll
    for (int j = 0; j < 8; ++j) s += bf2f(v[j]);
  }
  red[threadIdx.x] = s;
  __syncthreads();
  for (int o = 128; o > 0; o >>= 1) {
    if (threadIdx.x < o) red[threadIdx.x] += red[threadIdx.x + o];
    __syncthreads();
  }
  if (threadIdx.x == 0) denom[row] += red[0];
}

// ---------------- finalize: out = 0.5*ve[batch] + 0.5*numer/denom ----------------
__global__ void finalize(const float* __restrict__ parts, const float* __restrict__ denom,
                         const float* __restrict__ ve, const int* __restrict__ batch,
                         float* __restrict__ out) {
  int row = blockIdx.x;
  int t = threadIdx.x;
  float inv = 0.5f / denom[row];
  float4 a = *(const float4*)(ve + (size_t)batch[row] * DIM + (t << 2));
  float sx = 0.f, sy = 0.f, sz = 0.f, sw = 0.f;
  #pragma unroll
  for (int ks = 0; ks < KSPLIT; ++ks) {
    float4 pv = *(const float4*)(parts + ((size_t)ks * NTOK + row) * DIM + (t << 2));
    sx += pv.x; sy += pv.y; sz += pv.z; sw += pv.w;
  }
  float4 o;
  o.x = 0.5f * a.x + inv * sx;
  o.y = 0.5f * a.y + inv * sy;
  o.z = 0.5f * a.z + inv * sz;
  o.w = 0.5f * a.w + inv * sw;
  *(float4*)(out + (size_t)row * DIM + (t << 2)) = o;
}

// ---------------- launch ----------------
extern "C" void kernel_launch(void* const* d_in, const int* in_sizes, int n_in,
                              void* d_out, int out_size, void* d_ws, size_t ws_size,
                              hipStream_t stream) {
  const int*   batch = (const int*)d_in[0];
  const float* lang  = (const float*)d_in[1];
  const float* key   = (const float*)d_in[2];
  const float* ve    = (const float*)d_in[3];
  const float* W     = (const float*)d_in[4];
  float* out = (float*)d_out;

  // fixed buffers
  const size_t szWt    = (size_t)DIM * DIM * 2;        //  2 MiB
  const size_t szQb    = (size_t)NTOK * DIM * 2;       //  8 MiB
  const size_t szQW    = (size_t)NTOK * DIM * 2;       //  8 MiB
  const size_t szParts = (size_t)KSPLIT * NTOK * DIM * 4;
  const size_t szDenom = (size_t)NTOK * 4;
  const size_t fixed = szWt + szQb + szQW + szParts + szDenom;

  // pick largest vocab chunk whose buffers fit ws_size (deterministic)
  const int opts[4] = {6400, 3200, 1280, 640};
  int CHUNK = 640;
  for (int i = 0; i < 4; ++i) {
    size_t need = fixed + (size_t)opts[i] * (NTOK * 2 + DIM * 4);
    if (need <= ws_size) { CHUNK = opts[i]; break; }
  }
  const int NCHUNK = VOCAB / CHUNK;

  char* ws = (char*)d_ws;
  u16*   Wt    = (u16*)(ws);
  u16*   qb    = (u16*)(ws + szWt);
  u16*   qW    = (u16*)(ws + szWt + szQb);
  float* parts = (float*)(ws + szWt + szQb + szQW);
  float* denom = (float*)(ws + szWt + szQb + szQW + szParts);
  char*  dyn   = ws + fixed;
  u16*   keyc  = (u16*)(dyn);                                   // CHUNK*DIM bf16
  u16*   veTc  = (u16*)(dyn + (size_t)CHUNK * DIM * 2);         // DIM*CHUNK bf16
  u16*   Pc    = (u16*)(dyn + (size_t)CHUNK * DIM * 4);         // NTOK*CHUNK bf16

  // prologue
  transpose_cvt<<<dim3(DIM / 64, DIM / 64), 256, 0, stream>>>(W, Wt, DIM, DIM);
  gather_q<<<NTOK, 256, 0, stream>>>(batch, lang, qb);
  gemm_bt<3><<<dim3(NTOK / 128, DIM / 128), 256, 0, stream>>>(qb, Wt, qW, DIM, DIM / 32, DIM);
  hipMemsetAsync(parts, 0, szParts, stream);
  hipMemsetAsync(denom, 0, szDenom, stream);

  // vocab chunks
  for (int c = 0; c < NCHUNK; ++c) {
    const int v0 = c * CHUNK;
    cvt_f32_bf16<<<CHUNK * DIM / 1024, 256, 0, stream>>>(key + (size_t)v0 * DIM, keyc);
    transpose_cvt<<<dim3(CHUNK / 64, DIM / 64), 256, 0, stream>>>(ve + (size_t)v0 * DIM, veTc,
                                                                  DIM, CHUNK);
    gemm_bt<1><<<dim3(NTOK / 128, CHUNK / 128), 256, 0, stream>>>(qW, keyc, Pc,
                                                                  DIM, DIM / 32, CHUNK);
    rowsum_acc<<<NTOK, 256, 0, stream>>>(Pc, denom, CHUNK);
    gemm_bt<2><<<dim3(NTOK / 128, DIM / 128, KSPLIT), 256, 0, stream>>>(Pc, veTc, parts,
                                                                        CHUNK, CHUNK / 32 / KSPLIT, DIM);
  }

  finalize<<<NTOK, 256, 0, stream>>>(parts, denom, ve, batch, out);
}